// Round 1
// baseline (107.675 us; speedup 1.0000x reference)
//
#include <hip/hip_runtime.h>
#include <math.h>

#pragma clang fp contract(off)

#define NRAYS 4096
#define NS 512
#define NEL (NRAYS * NS)          // 2097152
#define TOPK 4000u

// d_out layout (floats), concatenated in reference return order
#define OFF_W     ((size_t)0)
#define OFF_BG    ((size_t)2097152)
#define OFF_DEPTH ((size_t)2101248)
#define OFF_FULL  ((size_t)2105344)
#define OFF_INV   ((size_t)4202496)

// ws layout (uints)
#define ST_DONE  0
#define ST_SEL1  1
#define ST_BASE  2
#define ST_SEL2  3
#define ST_TBITS 4
#define ST_M     5
#define ST_TIEN  6
#define WS_H1    16
#define WS_H2    (16 + 2048)
#define WS_H3    (16 + 4096)
#define WS_TIE   (16 + 5120)
#define TIE_CAP  8192u

__device__ __forceinline__ float tri_sample(const float* __restrict__ vol, int R,
                                            float cx, float cy, float cz) {
  #pragma clang fp contract(off)
  float c0 = fminf(fmaxf(cx, -1.0f), 1.0f);
  float c1 = fminf(fmaxf(cy, -1.0f), 1.0f);
  float c2 = fminf(fmaxf(cz, -1.0f), 1.0f);
  float fR = (float)(R - 1);
  float x = (c0 + 1.0f) * 0.5f * fR;
  float y = (c1 + 1.0f) * 0.5f * fR;
  float z = (c2 + 1.0f) * 0.5f * fR;
  float xf = fminf(fmaxf(floorf(x), 0.0f), (float)(R - 2));
  float yf = fminf(fmaxf(floorf(y), 0.0f), (float)(R - 2));
  float zf = fminf(fmaxf(floorf(z), 0.0f), (float)(R - 2));
  int x0 = (int)xf, y0 = (int)yf, z0 = (int)zf;
  float xd = x - xf, yd = y - yf, zd = z - zf;
  const float* p = vol + ((size_t)z0 * R + (size_t)y0) * R + (size_t)x0;
  float c000 = p[0], c001 = p[1];
  float c010 = p[R], c011 = p[R + 1];
  const float* q = p + (size_t)R * R;
  float c100 = q[0], c101 = q[1];
  float c110 = q[R], c111 = q[R + 1];
  float omx = 1.0f - xd, omy = 1.0f - yd, omz = 1.0f - zd;
  float c00 = c000 * omx + c001 * xd;
  float c01 = c010 * omx + c011 * xd;
  float c10 = c100 * omx + c101 * xd;
  float c11 = c110 * omx + c111 * xd;
  float a0 = c00 * omy + c01 * yd;
  float a1 = c10 * omy + c11 * yd;
  return a0 * omz + a1 * zd;
}

__global__ __launch_bounds__(256) void k_march(
    const float* __restrict__ ro, const float* __restrict__ rd,
    const float* __restrict__ dens, const float* __restrict__ prb,
    const float* __restrict__ alpv, float* __restrict__ out) {
  #pragma clang fp contract(off)
  const float STEP = (float)(3.0 * 1.7320508075688772 / 512.0);
  const float DIST = (float)((3.0 * 1.7320508075688772 / 512.0) * 25.0);
  const float INVG = 2.0f / 3.0f;
  int r = blockIdx.x;
  int t = threadIdx.x;
  __shared__ __align__(16) float s_alpha[NS];
  __shared__ float s_T[NS + 1];
  __shared__ float red[256];

  float ox = ro[r * 3 + 0], oy = ro[r * 3 + 1], oz = ro[r * 3 + 2];
  float dx = rd[r * 3 + 0], dy = rd[r * 3 + 1], dz = rd[r * 3 + 2];
  float vx = (dx == 0.0f) ? 1e-6f : dx;
  float vy = (dy == 0.0f) ? 1e-6f : dy;
  float vz = (dz == 0.0f) ? 1e-6f : dz;
  float tmin;
  {
    float rax = (1.5f - ox) / vx, rbx = (-1.5f - ox) / vx;
    float ray = (1.5f - oy) / vy, rby = (-1.5f - oy) / vy;
    float raz = (1.5f - oz) / vz, rbz = (-1.5f - oz) / vz;
    float m0 = fminf(rax, rbx), m1 = fminf(ray, rby), m2 = fminf(raz, rbz);
    tmin = fmaxf(fmaxf(m0, m1), m2);
    tmin = fminf(fmaxf(tmin, 2.0f), 6.0f);
  }

  // phase 1: alpha per sample
  for (int j = 0; j < 2; j++) {
    int s = t + j * 256;
    float ts = tmin + STEP * (float)s;
    float px = ox + dx * ts;
    float py = oy + dy * ts;
    float pz = oz + dz * ts;
    bool inb = !((-1.5f > px) || (px > 1.5f) || (-1.5f > py) || (py > 1.5f) ||
                 (-1.5f > pz) || (pz > 1.5f));
    float a = 0.0f;
    if (inb) {
      float nx = (px + 1.5f) * INVG - 1.0f;
      float ny = (py + 1.5f) * INVG - 1.0f;
      float nz = (pz + 1.5f) * INVG - 1.0f;
      float al = tri_sample(alpv, 128, nx, ny, nz);
      if (al > 0.001f) {
        float feat = tri_sample(dens, 256, nx, ny, nz);
        float xx = feat + (-10.0f);
        float sp = fmaxf(xx, 0.0f) + log1pf(expf(-fabsf(xx)));
        a = 1.0f - expf(-(sp * DIST));
      }
    }
    s_alpha[s] = a;
  }
  __syncthreads();

  // sequential cumprod (matches numpy left-to-right rounding)
  if (t == 0) {
    float T = 1.0f;
    s_T[0] = 1.0f;
    const float4* a4 = (const float4*)s_alpha;
    for (int i = 0; i < NS; i += 4) {
      float4 av = a4[i >> 2];
      T = T * ((1.0f - av.x) + 1e-10f); s_T[i + 1] = T;
      T = T * ((1.0f - av.y) + 1e-10f); s_T[i + 2] = T;
      T = T * ((1.0f - av.z) + 1e-10f); s_T[i + 3] = T;
      T = T * ((1.0f - av.w) + 1e-10f); s_T[i + 4] = T;
    }
  }
  __syncthreads();

  // phase 2: weights, depth, score (stash), app (stash)
  float dsum = 0.0f;
  for (int j = 0; j < 2; j++) {
    int s = t + j * 256;
    float w = s_alpha[s] * s_T[s];
    out[OFF_W + (size_t)r * NS + s] = w;
    float ts = tmin + STEP * (float)s;
    dsum += w * ts;
    float sc = 0.0f;
    float app = 0.0f;
    if (w > 1e-4f) {
      app = 1.0f;
      float px = ox + dx * ts;
      float py = oy + dy * ts;
      float pz = oz + dz * ts;
      float nx = (px + 1.5f) * INVG - 1.0f;
      float ny = (py + 1.5f) * INVG - 1.0f;
      float nz = (pz + 1.5f) * INVG - 1.0f;
      float pv = tri_sample(prb, 256, nx, ny, nz);
      sc = w * pv;
    }
    out[OFF_FULL + (size_t)r * NS + s] = sc;   // score stash
    out[OFF_INV + (size_t)r * NS + s] = app;   // app stash
  }
  red[t] = dsum;
  __syncthreads();
  for (int off = 128; off > 0; off >>= 1) {
    if (t < off) red[t] += red[t + off];
    __syncthreads();
  }
  if (t == 0) {
    out[OFF_DEPTH + r] = red[0];
    out[OFF_BG + r] = s_T[NS];
  }
}

__global__ void k_hist1(const float* __restrict__ score, unsigned* __restrict__ h1) {
  __shared__ unsigned sh[2048];
  for (int i = threadIdx.x; i < 2048; i += 256) sh[i] = 0u;
  __syncthreads();
  int idx = blockIdx.x * blockDim.x + threadIdx.x;
  int stride = gridDim.x * blockDim.x;
  for (int i = idx; i < NEL; i += stride) {
    unsigned u = __float_as_uint(score[i]);
    if (u) atomicAdd(&sh[u >> 21], 1u);
  }
  __syncthreads();
  for (int i = threadIdx.x; i < 2048; i += 256) {
    unsigned v = sh[i];
    if (v) atomicAdd(&h1[i], v);
  }
}

__global__ void k_hist2(const float* __restrict__ score, const unsigned* __restrict__ state,
                        unsigned* __restrict__ h2) {
  if (state[ST_DONE]) return;
  unsigned sel1 = state[ST_SEL1];
  int idx = blockIdx.x * blockDim.x + threadIdx.x;
  int stride = gridDim.x * blockDim.x;
  for (int i = idx; i < NEL; i += stride) {
    unsigned u = __float_as_uint(score[i]);
    if (u && (u >> 21) == sel1) atomicAdd(&h2[(u >> 10) & 0x7FFu], 1u);
  }
}

__global__ void k_hist3(const float* __restrict__ score, const unsigned* __restrict__ state,
                        unsigned* __restrict__ h3) {
  if (state[ST_DONE]) return;
  unsigned sel12 = (state[ST_SEL1] << 11) | state[ST_SEL2];
  int idx = blockIdx.x * blockDim.x + threadIdx.x;
  int stride = gridDim.x * blockDim.x;
  for (int i = idx; i < NEL; i += stride) {
    unsigned u = __float_as_uint(score[i]);
    if (u && (u >> 10) == sel12) atomicAdd(&h3[u & 0x3FFu], 1u);
  }
}

__global__ __launch_bounds__(1024) void k_find(unsigned* __restrict__ state,
                                               const unsigned* __restrict__ hist,
                                               int nbins, int stage) {
  __shared__ unsigned s[2048];
  int t = threadIdx.x;
  s[t] = (t < nbins) ? hist[t] : 0u;
  s[t + 1024] = (t + 1024 < nbins) ? hist[t + 1024] : 0u;
  __syncthreads();
  if (stage > 1 && state[ST_DONE]) return;
  // inclusive suffix scan over 2048 bins (Hillis-Steele)
  for (int off = 1; off < 2048; off <<= 1) {
    unsigned a0 = (t + off < 2048) ? s[t + off] : 0u;
    unsigned a1 = (t + 1024 + off < 2048) ? s[t + 1024 + off] : 0u;
    __syncthreads();
    s[t] += a0;
    s[t + 1024] += a1;
    __syncthreads();
  }
  unsigned base = (stage == 1) ? 0u : state[ST_BASE];
  if (stage == 1 && base + s[0] < TOPK) {
    if (t == 0) { state[ST_DONE] = 1u; state[ST_TBITS] = 0u; state[ST_M] = 0u; }
    return;
  }
  for (int i = t; i < nbins; i += 1024) {
    unsigned hi = (i + 1 < nbins) ? s[i + 1] : 0u;
    if (base + s[i] >= TOPK && base + hi < TOPK) {
      if (stage == 1) {
        state[ST_SEL1] = (unsigned)i; state[ST_BASE] = base + hi;
      } else if (stage == 2) {
        state[ST_SEL2] = (unsigned)i; state[ST_BASE] = base + hi;
      } else {
        unsigned tb = (state[ST_SEL1] << 21) | (state[ST_SEL2] << 10) | (unsigned)i;
        state[ST_TBITS] = tb;
        state[ST_M] = TOPK - (base + hi);
      }
    }
  }
}

__global__ void k_tie(const float* __restrict__ score, unsigned* __restrict__ state,
                      unsigned* __restrict__ tie) {
  unsigned tb = state[ST_TBITS];
  if (tb == 0u) return;
  int idx = blockIdx.x * blockDim.x + threadIdx.x;
  int stride = gridDim.x * blockDim.x;
  for (int i = idx; i < NEL; i += stride) {
    if (__float_as_uint(score[i]) == tb) {
      unsigned p = atomicAdd(&state[ST_TIEN], 1u);
      if (p < TIE_CAP) tie[p] = (unsigned)i;
    }
  }
}

__global__ __launch_bounds__(256) void k_mask(float* __restrict__ out,
                                              const unsigned* __restrict__ state) {
  unsigned tb = state[ST_TBITS];
  float Tf = __uint_as_float(tb);
  size_t i = (size_t)blockIdx.x * 256 + threadIdx.x;
  float sc = out[OFF_FULL + i];
  float app = out[OFF_INV + i];
  bool full = (tb == 0u) ? (sc > 0.0f) : (sc > Tf);
  out[OFF_FULL + i] = full ? 1.0f : 0.0f;
  out[OFF_INV + i] = (app != 0.0f && !full) ? 1.0f : 0.0f;
}

__global__ void k_patch(float* __restrict__ out, unsigned* __restrict__ state,
                        unsigned* __restrict__ tie) {
  if (threadIdx.x != 0 || blockIdx.x != 0) return;
  unsigned tb = state[ST_TBITS];
  if (tb == 0u) return;
  unsigned n = state[ST_TIEN];
  if (n > TIE_CAP) n = TIE_CAP;
  unsigned m = state[ST_M];
  if (m > n) m = n;
  for (unsigned k = 0; k < m; k++) {
    unsigned best = k;
    for (unsigned j = k + 1; j < n; j++)
      if (tie[j] < tie[best]) best = j;
    unsigned tmp = tie[k]; tie[k] = tie[best]; tie[best] = tmp;
    out[OFF_FULL + tie[k]] = 1.0f;
    out[OFF_INV + tie[k]] = 0.0f;
  }
}

extern "C" void kernel_launch(void* const* d_in, const int* in_sizes, int n_in,
                              void* d_out, int out_size, void* d_ws, size_t ws_size,
                              hipStream_t stream) {
  const float* ro = (const float*)d_in[0];
  const float* rd = (const float*)d_in[1];
  const float* dens = (const float*)d_in[2];
  const float* prb = (const float*)d_in[3];
  const float* alpv = (const float*)d_in[4];
  float* out = (float*)d_out;
  unsigned* ws = (unsigned*)d_ws;
  unsigned* state = ws;
  unsigned* h1 = ws + WS_H1;
  unsigned* h2 = ws + WS_H2;
  unsigned* h3 = ws + WS_H3;
  unsigned* tie = ws + WS_TIE;

  hipMemsetAsync(ws, 0, (16 + 5120) * sizeof(unsigned), stream);
  k_march<<<NRAYS, 256, 0, stream>>>(ro, rd, dens, prb, alpv, out);
  k_hist1<<<512, 256, 0, stream>>>(out + OFF_FULL, h1);
  k_find<<<1, 1024, 0, stream>>>(state, h1, 2048, 1);
  k_hist2<<<512, 256, 0, stream>>>(out + OFF_FULL, state, h2);
  k_find<<<1, 1024, 0, stream>>>(state, h2, 2048, 2);
  k_hist3<<<512, 256, 0, stream>>>(out + OFF_FULL, state, h3);
  k_find<<<1, 1024, 0, stream>>>(state, h3, 1024, 3);
  k_tie<<<512, 256, 0, stream>>>(out + OFF_FULL, state, tie);
  k_mask<<<NEL / 256, 256, 0, stream>>>(out, state);
  k_patch<<<1, 64, 0, stream>>>(out, state, tie);
}